// Round 13
// baseline (385.723 us; speedup 1.0000x reference)
//
#include <hip/hip_runtime.h>
#include <hip/hip_bf16.h>
#include <stdint.h>

// Problem: N=512, S=256, D=512, C=1024, CLASSES=1000 (all fp32 in/out)
// d_out = [logits 512x1000][recon 512x512][ew 512x256] fp32 flat.
// d_ws (fused, ws>=7MB): [0,1MB) cbB bf16 | [1,3MB) cw | [3,7MB) partial sums
// d_ws (fallback):       [0,1MB) cbB      | [1,3MB) cw | [3,4MB) sm

typedef float  f32x4 __attribute__((ext_vector_type(4)));
typedef float  f32x2 __attribute__((ext_vector_type(2)));
typedef short  s16x8 __attribute__((ext_vector_type(8)));

__device__ __forceinline__ unsigned short f2bf(float x){
  unsigned u = __float_as_uint(x);
  u += 0x7fffu + ((u >> 16) & 1u);           // RNE
  return (unsigned short)(u >> 16);
}
__device__ __forceinline__ float hsum4(f32x4 v){ return v[0]+v[1]+v[2]+v[3]; }

static constexpr float INV_SCALE = 0.04419417382415922f; // 1/sqrt(512)

// ---------------------------------------------------------------------------
// Kernel PREP: blocks 0..255 = codebook fp32->bf16*(1/sqrt D) into 32c-panel
// cbB; blocks 256..319 = q_proj + cw softmax (8 n per block: halves codebook
// re-reads vs 4 n/block).
// ---------------------------------------------------------------------------
__global__ __launch_bounds__(256) void k_prep(const float* __restrict__ cb,
                                              unsigned short* __restrict__ cbB,
                                              const float* __restrict__ q,
                                              const float* __restrict__ Wq,
                                              float* __restrict__ cw){
  __shared__ __align__(16) float qrow[8][512];
  __shared__ __align__(16) float qproj[8][512];
  __shared__ float ev[8][1024];
  __shared__ float red[256];
  __shared__ float tot[8];
  const int t = threadIdx.x;

  if (blockIdx.x < 256){
    const int g = blockIdx.x*256 + t;            // 0..65535, 8 elems each
    const int ks8 = g & 3;
    const int cr  = (g >> 2) & 31;
    const int kk  = (g >> 7) & 15;
    const int p   = g >> 11;
    const int c = p*32 + cr;
    const int k = kk*32 + ks8*8;
    const float* src = cb + (size_t)c*512 + k;
    const f32x4 v0 = *(const f32x4*)(src);
    const f32x4 v1 = *(const f32x4*)(src + 4);
    s16x8 o;
    o[0]=(short)f2bf(v0[0]*INV_SCALE); o[1]=(short)f2bf(v0[1]*INV_SCALE);
    o[2]=(short)f2bf(v0[2]*INV_SCALE); o[3]=(short)f2bf(v0[3]*INV_SCALE);
    o[4]=(short)f2bf(v1[0]*INV_SCALE); o[5]=(short)f2bf(v1[1]*INV_SCALE);
    o[6]=(short)f2bf(v1[2]*INV_SCALE); o[7]=(short)f2bf(v1[3]*INV_SCALE);
    *(s16x8*)(cbB + (size_t)g*8) = o;
    return;
  }

  // ---- cw path: 8 n per block ----
  const int n0 = (blockIdx.x - 256)*8;
  #pragma unroll
  for (int j = 0; j < 16; ++j){
    const int o = t + 256*j; const int ni = o >> 9, d = o & 511;
    qrow[ni][d] = q[(size_t)(n0+ni)*512 + d];
  }
  __syncthreads();
  {
    #pragma unroll 1
    for (int j = 0; j < 2; ++j){
      const int e = t + 256*j;
      const f32x4* w4 = (const f32x4*)(Wq + (size_t)e*512);
      f32x4 av[8];
      #pragma unroll
      for (int ni = 0; ni < 8; ++ni) av[ni] = (f32x4){0,0,0,0};
      for (int d = 0; d < 128; ++d){
        const f32x4 wv = w4[d];
        #pragma unroll
        for (int ni = 0; ni < 8; ++ni)
          av[ni] += wv * ((const f32x4*)qrow[ni])[d];
      }
      #pragma unroll
      for (int ni = 0; ni < 8; ++ni) qproj[ni][e] = hsum4(av[ni]);
    }
  }
  __syncthreads();
  {
    #pragma unroll 1
    for (int j = 0; j < 4; ++j){
      const int c = t + 256*j;
      const f32x4* c4 = (const f32x4*)(cb + (size_t)c*512);
      f32x4 av[8];
      #pragma unroll
      for (int ni = 0; ni < 8; ++ni) av[ni] = (f32x4){0,0,0,0};
      for (int d = 0; d < 128; ++d){
        const f32x4 wv = c4[d];
        #pragma unroll
        for (int ni = 0; ni < 8; ++ni)
          av[ni] += wv * ((const f32x4*)qproj[ni])[d];
      }
      #pragma unroll
      for (int ni = 0; ni < 8; ++ni)
        ev[ni][c] = __expf(hsum4(av[ni])*INV_SCALE);
    }
  }
  __syncthreads();
  for (int ni = 0; ni < 8; ++ni){
    red[t] = ev[ni][t] + ev[ni][t+256] + ev[ni][t+512] + ev[ni][t+768];
    __syncthreads();
    for (int off = 128; off > 0; off >>= 1){
      if (t < off) red[t] += red[t+off];
      __syncthreads();
    }
    if (t == 0) tot[ni] = red[0];
    __syncthreads();
  }
  #pragma unroll
  for (int j = 0; j < 32; ++j){
    const int o = t + 256*j; const int ni = o >> 10, c = o & 1023;
    cw[(size_t)(n0+ni)*1024 + c] = ev[ni][c] / tot[ni];
  }
}

// ---------------------------------------------------------------------------
// Kernel B: r12 memory plan + A-READS 2 ITERATIONS AHEAD with counted
// s_waitcnt lgkmcnt(4). Per kk: wait vmcnt(2) [b(kk)] + lgkmcnt(4) [a(kk)]
// -> 8 MFMA -> issue a(kk+2), b(kk+2) into the just-consumed slots.
// A-read lead = one full iteration (~180 cyc) >> 120-cyc ds latency (the
// r7 1-ahead variant gave only ~60 cyc of lead - insufficient).
// Regs: a[2][4]=32 + b[2][2]=16 + acc[4][2]=32 AGPR + temps ~= 100 < 128.
// es/ws dropped (spill safety); per-pass ladders accumulate into pe/pw.
// ---------------------------------------------------------------------------
template<bool FUSE_V>
__global__ __launch_bounds__(512, 4) void k_scores(const float* __restrict__ Kt,
                                                   const unsigned short* __restrict__ cbB,
                                                   const float* __restrict__ cw,
                                                   float* __restrict__ ew_out,
                                                   const float* __restrict__ Vp,
                                                   float* __restrict__ partial){
  __shared__ __align__(16) short sA[64*512];      // 64 KB
  __shared__ float cwl[1024];                     // 4 KB
  __shared__ float pe[8][64];                     // 2 KB
  __shared__ float pw[8][64];                     // 2 KB
  __shared__ float ewl[64];                       // 256 B

  const int t    = threadIdx.x;
  const int lane = t & 63;
  const int w    = t >> 6;
  const int m0   = blockIdx.x * 64;   // row base (n*256+s); 64|256 -> one n
  const int n    = m0 >> 8;

  // ---- stage A tile: fp32 -> bf16 (RNE), slot ^= (row&7) swizzle ----
  {
    const int row = t >> 3;
    const float* src = Kt + (size_t)(m0 + row) * 512;
    #pragma unroll
    for (int j = 0; j < 8; ++j){
      const int slot = (t & 7) + 8*j;
      const f32x4 v0 = *(const f32x4*)(src + slot*8);
      const f32x4 v1 = *(const f32x4*)(src + slot*8 + 4);
      s16x8 o;
      o[0]=(short)f2bf(v0[0]); o[1]=(short)f2bf(v0[1]); o[2]=(short)f2bf(v0[2]); o[3]=(short)f2bf(v0[3]);
      o[4]=(short)f2bf(v1[0]); o[5]=(short)f2bf(v1[1]); o[6]=(short)f2bf(v1[2]); o[7]=(short)f2bf(v1[3]);
      const int sp = slot ^ (row & 7);
      *(s16x8*)&sA[row*512 + sp*8] = o;
    }
  }
  cwl[t]       = cw[(size_t)n*1024 + t];
  cwl[t + 512] = cw[(size_t)n*1024 + t + 512];
  pe[w][lane] = 0.f;
  pw[w][lane] = 0.f;
  __syncthreads();

  const int kg = lane >> 4;
  const int lr = lane & 15;
  const int rot = blockIdx.x & 3;     // L2 de-hotspot rotation

  #pragma unroll 1
  for (int p = 0; p < 4; ++p){
    const int ci = (p + rot) & 3;
    f32x4 acc[4][2];
    #pragma unroll
    for (int fr = 0; fr < 4; ++fr)
      #pragma unroll
      for (int fc = 0; fc < 2; ++fc) acc[fr][fc] = (f32x4){0.f,0.f,0.f,0.f};

    const unsigned short* pbase = cbB + ((size_t)(ci*8 + w))*16384;
    const int loff = lr*32 + kg*8;

    s16x8 a[2][4], b[2][2];
    // ---- prologue: b(0), b(1) [4 vm loads]; a(0), a(1) [8 ds reads] ----
    #pragma unroll
    for (int fc = 0; fc < 2; ++fc)
      b[0][fc] = *(const s16x8*)(pbase + 0*1024 + fc*512 + loff);
    #pragma unroll
    for (int fc = 0; fc < 2; ++fc)
      b[1][fc] = *(const s16x8*)(pbase + 1*1024 + fc*512 + loff);
    #pragma unroll
    for (int u = 0; u < 2; ++u)
      #pragma unroll
      for (int fr = 0; fr < 4; ++fr){
        const int row = fr*16 + lr;
        const int sp  = (u*4 + kg) ^ (row & 7);
        a[u][fr] = *(const s16x8*)&sA[row*512 + sp*8];
      }

    #pragma unroll
    for (int kk = 0; kk < 16; ++kk){
      // b(kk) landed (2 newer in flight), a(kk) landed (4 newer in flight)
      if (kk < 14)      asm volatile("s_waitcnt vmcnt(2) lgkmcnt(4)" ::: "memory");
      else if (kk == 14) asm volatile("s_waitcnt vmcnt(2) lgkmcnt(4)" ::: "memory");
      else              asm volatile("s_waitcnt vmcnt(0) lgkmcnt(0)" ::: "memory");
      __builtin_amdgcn_sched_barrier(0);
      __builtin_amdgcn_s_setprio(1);
      #pragma unroll
      for (int fr = 0; fr < 4; ++fr)
        #pragma unroll
        for (int fc = 0; fc < 2; ++fc)
          acc[fr][fc] = __builtin_amdgcn_mfma_f32_16x16x32_bf16(a[kk & 1][fr], b[kk & 1][fc], acc[fr][fc], 0, 0, 0);
      __builtin_amdgcn_s_setprio(0);
      __builtin_amdgcn_sched_barrier(0);
      // refill the just-consumed slots with kk+2 (WAR-safe: cluster kk done)
      if (kk < 14){
        #pragma unroll
        for (int fr = 0; fr < 4; ++fr){
          const int row = fr*16 + lr;
          const int sp  = ((kk+2)*4 + kg) ^ (row & 7);
          a[kk & 1][fr] = *(const s16x8*)&sA[row*512 + sp*8];
        }
        #pragma unroll
        for (int fc = 0; fc < 2; ++fc)
          b[kk & 1][fc] = *(const s16x8*)(pbase + (size_t)(kk+2)*1024 + fc*512 + loff);
      }
      __builtin_amdgcn_sched_barrier(0);
    }

    // per-pass epilogue: exp + cw-weight + 16-lane ladder into pe/pw (+=)
    const float cwv0 = cwl[ci*256 + w*32 + 0*16 + lr];
    const float cwv1 = cwl[ci*256 + w*32 + 1*16 + lr];
    #pragma unroll
    for (int fr = 0; fr < 4; ++fr){
      float es[4], ws[4];
      #pragma unroll
      for (int r = 0; r < 4; ++r){
        const float e0 = __expf(acc[fr][0][r]);   // scale pre-folded into cb
        const float e1 = __expf(acc[fr][1][r]);
        es[r] = e0 + e1;
        ws[r] = e0 * cwv0 + e1 * cwv1;
      }
      #pragma unroll
      for (int r = 0; r < 4; ++r){
        float a0 = es[r], b0 = ws[r];
        #pragma unroll
        for (int m = 1; m < 16; m <<= 1){
          a0 += __shfl_xor(a0, m, 64);
          b0 += __shfl_xor(b0, m, 64);
        }
        if (lr == 0){
          const int row = fr*16 + kg*4 + r;   // C/D map: row=(l>>4)*4+reg
          pe[w][row] += a0;
          pw[w][row] += b0;
        }
      }
    }
  }

  __syncthreads();
  if (t < 64){
    float se = 0.f, sw = 0.f;
    #pragma unroll
    for (int i = 0; i < 8; ++i){ se += pe[i][t]; sw += pw[i][t]; }
    const float e = sw / se;
    ew_out[m0 + t] = e;
    ewl[t] = e;
  }

  if constexpr (FUSE_V){
    __syncthreads();                       // ewl ready; sA dead -> reuse
    float* psum = (float*)sA;              // [4][512] f32 = 8 KB
    const int sh = t >> 7;                 // s-quarter 0..3
    const int dq = (t & 127) * 4;          // d offset
    const float* vb = Vp + (size_t)m0*512 + dq;
    f32x4 av = {0.f,0.f,0.f,0.f};
    #pragma unroll
    for (int i = 0; i < 16; ++i){
      const int s = sh*16 + i;
      av += ewl[s] * *(const f32x4*)(vb + (size_t)s*512);
    }
    *(f32x4*)&psum[sh*512 + dq] = av;
    __syncthreads();
    if (t < 128){
      const int d4 = t*4;
      f32x4 r = *(f32x4*)&psum[d4];
      r += *(f32x4*)&psum[512 + d4];
      r += *(f32x4*)&psum[1024 + d4];
      r += *(f32x4*)&psum[1536 + d4];
      *(f32x4*)&partial[(size_t)blockIdx.x*512 + d4] = r;
    }
  }
}

// ---------------------------------------------------------------------------
// Kernel C (fallback only): summary[n][d] = sum_s ew[n,s] * V[n,s,d].
// ---------------------------------------------------------------------------
__global__ __launch_bounds__(256) void k_summary(const float* __restrict__ V,
                                                 const float* __restrict__ ew,
                                                 float* __restrict__ sm){
  __shared__ float e[256];
  __shared__ f32x4 red[3][64];
  const int t = threadIdx.x;
  const int lane = t & 63, w = t >> 6;
  const int n = blockIdx.x >> 1;
  const int d0 = (blockIdx.x & 1) * 256;
  e[t] = ew[(size_t)n*256 + t];
  __syncthreads();
  const float* vb = V + (size_t)n*131072 + d0 + lane*4;
  f32x4 acc = {0.f,0.f,0.f,0.f};
  #pragma unroll 8
  for (int s = w; s < 256; s += 4){
    const f32x4 v = *(const f32x4*)(vb + (size_t)s*512);
    acc += e[s] * v;
  }
  if (w > 0) red[w-1][lane] = acc;
  __syncthreads();
  if (w == 0){
    acc += red[0][lane] + red[1][lane] + red[2][lane];
    *(f32x4*)(sm + (size_t)n*512 + d0 + lane*4) = acc;
  }
}

// ---------------------------------------------------------------------------
// Kernel D: logits/recon readout. FUSED: src = partial[2048][512], summary
// row ni = sum of 4 partials. Else src = sm[512][512].
// grid = 64 n-blocks (8 n) x 4 W-slices = 256 blocks.
// ---------------------------------------------------------------------------
template<bool FUSED>
__global__ __launch_bounds__(256) void k_readout(const float* __restrict__ src,
                                                 const float* __restrict__ Wc,
                                                 const float* __restrict__ bc,
                                                 const float* __restrict__ Wr,
                                                 const float* __restrict__ br,
                                                 float* __restrict__ logits,
                                                 float* __restrict__ recon){
  __shared__ __align__(16) float sl[8][512];
  const int t = threadIdx.x;
  const int nb  = blockIdx.x >> 2;
  const int wsl = blockIdx.x & 3;
  const int n0 = nb * 8;
  #pragma unroll
  for (int j = 0; j < 16; ++j){
    const int o = t + 256*j; const int ni = o >> 9, d = o & 511;
    if (FUSED){
      const float* pb = src + (size_t)(n0+ni)*2048 + d;
      sl[ni][d] = pb[0] + pb[512] + pb[1024] + pb[1536];
    } else {
      sl[ni][d] = src[(size_t)(n0+ni)*512 + d];
    }
  }
  __syncthreads();
  #pragma unroll 1
  for (int j = 0; j < 2; ++j){
    const int rel = t + 256*j;
    if (rel >= 378) continue;
    const int o = wsl*378 + rel;          // 0..1511
    const bool isl = o < 1000;
    const float* wrow = isl ? (Wc + (size_t)o*512) : (Wr + (size_t)(o-1000)*512);
    const float bias  = isl ? bc[o] : br[o-1000];
    const f32x4* w4 = (const f32x4*)wrow;
    f32x4 av[8];
    #pragma unroll
    for (int ni = 0; ni < 8; ++ni) av[ni] = (f32x4){0.f,0.f,0.f,0.f};
    for (int d = 0; d < 128; ++d){
      const f32x4 wv = w4[d];
      #pragma unroll
      for (int ni = 0; ni < 8; ++ni)
        av[ni] += wv * ((const f32x4*)sl[ni])[d];
    }
    #pragma unroll
    for (int ni = 0; ni < 8; ++ni){
      const float r = hsum4(av[ni]) + bias;
      if (isl) logits[(size_t)(n0+ni)*1000 + o] = r;
      else     recon [(size_t)(n0+ni)*512 + (o-1000)] = r;
    }
  }
}

extern "C" void kernel_launch(void* const* d_in, const int* in_sizes, int n_in,
                              void* d_out, int out_size, void* d_ws, size_t ws_size,
                              hipStream_t stream) {
  const float* q  = (const float*)d_in[0];
  const float* K  = (const float*)d_in[1];
  const float* V  = (const float*)d_in[2];
  const float* cb = (const float*)d_in[3];
  const float* Wq = (const float*)d_in[4];
  const float* Wc = (const float*)d_in[5];
  const float* bc = (const float*)d_in[6];
  const float* Wr = (const float*)d_in[7];
  const float* br = (const float*)d_in[8];

  float* out    = (float*)d_out;
  float* logits = out;                         // 512*1000
  float* recon  = out + 512*1000;              // 512*512
  float* ew     = out + 512*1000 + 512*512;    // 512*256

  char* wsb = (char*)d_ws;
  unsigned short* cbB = (unsigned short*)wsb;            // 1 MB
  float* cw   = (float*)(wsb + (1u<<20));                // 2 MB
  float* aux  = (float*)(wsb + 3u*(1u<<20));             // partials (4MB) or sm (1MB)

  const bool fused = ws_size >= (size_t)(7u<<20);

  k_prep<<<dim3(320), dim3(256), 0, stream>>>(cb, cbB, q, Wq, cw);
  if (fused){
    k_scores<true><<<dim3(2048), dim3(512), 0, stream>>>(K, cbB, cw, ew, V, aux);
    k_readout<true><<<dim3(256), dim3(256), 0, stream>>>(aux, Wc, bc, Wr, br, logits, recon);
  } else {
    k_scores<false><<<dim3(2048), dim3(512), 0, stream>>>(K, cbB, cw, ew, V, aux);
    k_summary<<<dim3(1024), dim3(256), 0, stream>>>(V, ew, aux);
    k_readout<false><<<dim3(256), dim3(256), 0, stream>>>(aux, Wc, bc, Wr, br, logits, recon);
  }
}

// Round 14
// 360.186 us; speedup vs baseline: 1.0709x; 1.0709x over previous
//
#include <hip/hip_runtime.h>
#include <hip/hip_bf16.h>
#include <stdint.h>

// Problem: N=512, S=256, D=512, C=1024, CLASSES=1000 (all fp32 in/out)
// d_out = [logits 512x1000][recon 512x512][ew 512x256] fp32 flat.
// d_ws (fused, ws>=7MB): [0,1MB) cbB bf16 | [1,3MB) cw | [3,7MB) partial sums
// d_ws (fallback):       [0,1MB) cbB      | [1,3MB) cw | [3,4MB) sm
// This is the round-12 measured optimum (360 us), restored after r13's
// lgkm-lead experiment regressed (271->288 us k_scores).

typedef float  f32x4 __attribute__((ext_vector_type(4)));
typedef float  f32x2 __attribute__((ext_vector_type(2)));
typedef short  s16x8 __attribute__((ext_vector_type(8)));

__device__ __forceinline__ unsigned short f2bf(float x){
  unsigned u = __float_as_uint(x);
  u += 0x7fffu + ((u >> 16) & 1u);           // RNE
  return (unsigned short)(u >> 16);
}
__device__ __forceinline__ float hsum4(f32x4 v){ return v[0]+v[1]+v[2]+v[3]; }

static constexpr float INV_SCALE = 0.04419417382415922f; // 1/sqrt(512)

// ---------------------------------------------------------------------------
// Kernel PREP: blocks 0..255 = codebook fp32->bf16*(1/sqrt D) into 32c-panel
// cbB; blocks 256..383 = q_proj + cw softmax (4 n per block, 128 blocks).
// ---------------------------------------------------------------------------
__global__ __launch_bounds__(256) void k_prep(const float* __restrict__ cb,
                                              unsigned short* __restrict__ cbB,
                                              const float* __restrict__ q,
                                              const float* __restrict__ Wq,
                                              float* __restrict__ cw){
  __shared__ __align__(16) float qrow[4][512];
  __shared__ __align__(16) float qproj[4][512];
  __shared__ float ev[4][1024];
  __shared__ float red[256];
  __shared__ float tot[4];
  const int t = threadIdx.x;

  if (blockIdx.x < 256){
    // ---- cbarr: elem = ((p*16+kk)*32+cr)*32+ks, c=p*32+cr, k=kk*32+ks ----
    const int g = blockIdx.x*256 + t;            // 0..65535, 8 elems each
    const int ks8 = g & 3;
    const int cr  = (g >> 2) & 31;
    const int kk  = (g >> 7) & 15;
    const int p   = g >> 11;
    const int c = p*32 + cr;
    const int k = kk*32 + ks8*8;
    const float* src = cb + (size_t)c*512 + k;
    const f32x4 v0 = *(const f32x4*)(src);
    const f32x4 v1 = *(const f32x4*)(src + 4);
    s16x8 o;
    o[0]=(short)f2bf(v0[0]*INV_SCALE); o[1]=(short)f2bf(v0[1]*INV_SCALE);
    o[2]=(short)f2bf(v0[2]*INV_SCALE); o[3]=(short)f2bf(v0[3]*INV_SCALE);
    o[4]=(short)f2bf(v1[0]*INV_SCALE); o[5]=(short)f2bf(v1[1]*INV_SCALE);
    o[6]=(short)f2bf(v1[2]*INV_SCALE); o[7]=(short)f2bf(v1[3]*INV_SCALE);
    *(s16x8*)(cbB + (size_t)g*8) = o;
    return;
  }

  // ---- cw path: 4 n per block ----
  const int n0 = (blockIdx.x - 256)*4;
  #pragma unroll
  for (int j = 0; j < 8; ++j){
    const int o = t + 256*j; const int ni = o >> 9, d = o & 511;
    qrow[ni][d] = q[(size_t)(n0+ni)*512 + d];
  }
  __syncthreads();
  {
    const f32x4* q0 = (const f32x4*)qrow[0];
    const f32x4* q1 = (const f32x4*)qrow[1];
    const f32x4* q2 = (const f32x4*)qrow[2];
    const f32x4* q3 = (const f32x4*)qrow[3];
    #pragma unroll 1
    for (int j = 0; j < 2; ++j){
      const int e = t + 256*j;
      const f32x4* w4 = (const f32x4*)(Wq + (size_t)e*512);
      f32x4 a0={0,0,0,0},a1={0,0,0,0},a2={0,0,0,0},a3={0,0,0,0};
      for (int d = 0; d < 128; ++d){
        const f32x4 wv = w4[d];
        a0 += wv*q0[d]; a1 += wv*q1[d]; a2 += wv*q2[d]; a3 += wv*q3[d];
      }
      qproj[0][e]=hsum4(a0); qproj[1][e]=hsum4(a1); qproj[2][e]=hsum4(a2); qproj[3][e]=hsum4(a3);
    }
  }
  __syncthreads();
  {
    const f32x4* p0 = (const f32x4*)qproj[0];
    const f32x4* p1 = (const f32x4*)qproj[1];
    const f32x4* p2 = (const f32x4*)qproj[2];
    const f32x4* p3 = (const f32x4*)qproj[3];
    #pragma unroll 1
    for (int j = 0; j < 4; ++j){
      const int c = t + 256*j;
      const f32x4* c4 = (const f32x4*)(cb + (size_t)c*512);
      f32x4 a0={0,0,0,0},a1={0,0,0,0},a2={0,0,0,0},a3={0,0,0,0};
      for (int d = 0; d < 128; ++d){
        const f32x4 wv = c4[d];
        a0 += wv*p0[d]; a1 += wv*p1[d]; a2 += wv*p2[d]; a3 += wv*p3[d];
      }
      ev[0][c] = __expf(hsum4(a0)*INV_SCALE);
      ev[1][c] = __expf(hsum4(a1)*INV_SCALE);
      ev[2][c] = __expf(hsum4(a2)*INV_SCALE);
      ev[3][c] = __expf(hsum4(a3)*INV_SCALE);
    }
  }
  __syncthreads();
  for (int ni = 0; ni < 4; ++ni){
    red[t] = ev[ni][t] + ev[ni][t+256] + ev[ni][t+512] + ev[ni][t+768];
    __syncthreads();
    for (int off = 128; off > 0; off >>= 1){
      if (t < off) red[t] += red[t+off];
      __syncthreads();
    }
    if (t == 0) tot[ni] = red[0];
    __syncthreads();
  }
  #pragma unroll
  for (int j = 0; j < 16; ++j){
    const int o = t + 256*j; const int ni = o >> 10, c = o & 1023;
    cw[(size_t)(n0+ni)*1024 + c] = ev[ni][c] / tot[ni];
  }
}

// ---------------------------------------------------------------------------
// Kernel B (r10/r12 structure, best measured: 271 us incl. V-phase): 64 rows
// x 1024 c per block, wave tile 64x32, 4 rotated passes, B 2-deep from L2,
// regs-resident es/ws with one shuffle ladder. FUSE_V adds a V-phase: block
// computes its 64-row partial summary (psum reuses dead sA LDS).
// Reg law (r4/r9/r11): {acc 32 AGPR + a16 + b16 + es/ws 32} is the 128-cap
// maximum; anything more spills. Prefetch-depth law (r7/r13): added depth
// beyond this point is neutral-or-worse.
// ---------------------------------------------------------------------------
template<bool FUSE_V>
__global__ __launch_bounds__(512, 4) void k_scores(const float* __restrict__ Kt,
                                                   const unsigned short* __restrict__ cbB,
                                                   const float* __restrict__ cw,
                                                   float* __restrict__ ew_out,
                                                   const float* __restrict__ Vp,
                                                   float* __restrict__ partial){
  __shared__ __align__(16) short sA[64*512];      // 64 KB
  __shared__ float cwl[1024];                     // 4 KB
  __shared__ float pe[8][64];                     // 2 KB
  __shared__ float pw[8][64];                     // 2 KB
  __shared__ float ewl[64];                       // 256 B

  const int t    = threadIdx.x;
  const int lane = t & 63;
  const int w    = t >> 6;
  const int m0   = blockIdx.x * 64;   // row base (n*256+s); 64|256 -> one n
  const int n    = m0 >> 8;

  // ---- stage A tile: fp32 -> bf16 (RNE), slot ^= (row&7) swizzle ----
  {
    const int row = t >> 3;
    const float* src = Kt + (size_t)(m0 + row) * 512;
    #pragma unroll
    for (int j = 0; j < 8; ++j){
      const int slot = (t & 7) + 8*j;
      const f32x4 v0 = *(const f32x4*)(src + slot*8);
      const f32x4 v1 = *(const f32x4*)(src + slot*8 + 4);
      s16x8 o;
      o[0]=(short)f2bf(v0[0]); o[1]=(short)f2bf(v0[1]); o[2]=(short)f2bf(v0[2]); o[3]=(short)f2bf(v0[3]);
      o[4]=(short)f2bf(v1[0]); o[5]=(short)f2bf(v1[1]); o[6]=(short)f2bf(v1[2]); o[7]=(short)f2bf(v1[3]);
      const int sp = slot ^ (row & 7);
      *(s16x8*)&sA[row*512 + sp*8] = o;
    }
  }
  cwl[t]       = cw[(size_t)n*1024 + t];
  cwl[t + 512] = cw[(size_t)n*1024 + t + 512];
  __syncthreads();

  const int kg = lane >> 4;
  const int lr = lane & 15;
  const int rot = blockIdx.x & 3;     // L2 de-hotspot rotation

  float es[4][4], ws[4][4];
  #pragma unroll
  for (int fr = 0; fr < 4; ++fr)
    #pragma unroll
    for (int r = 0; r < 4; ++r){ es[fr][r] = 0.f; ws[fr][r] = 0.f; }

  #pragma unroll 1
  for (int p = 0; p < 4; ++p){
    const int ci = (p + rot) & 3;
    f32x4 acc[4][2];
    #pragma unroll
    for (int fr = 0; fr < 4; ++fr)
      #pragma unroll
      for (int fc = 0; fc < 2; ++fc) acc[fr][fc] = (f32x4){0.f,0.f,0.f,0.f};

    const unsigned short* pbase = cbB + ((size_t)(ci*8 + w))*16384;
    const int loff = lr*32 + kg*8;

    s16x8 a[4], b[2][2];
    #pragma unroll
    for (int fc = 0; fc < 2; ++fc)
      b[0][fc] = *(const s16x8*)(pbase + 0*1024 + fc*512 + loff);
    #pragma unroll
    for (int fc = 0; fc < 2; ++fc)
      b[1][fc] = *(const s16x8*)(pbase + 1*1024 + fc*512 + loff);

    #pragma unroll
    for (int kk = 0; kk < 16; ++kk){
      if (kk < 15) asm volatile("s_waitcnt vmcnt(2)" ::: "memory");
      else         asm volatile("s_waitcnt vmcnt(0)" ::: "memory");
      __builtin_amdgcn_sched_barrier(0);
      #pragma unroll
      for (int fr = 0; fr < 4; ++fr){
        const int row = fr*16 + lr;
        const int sp  = (kk*4 + kg) ^ (row & 7);
        a[fr] = *(const s16x8*)&sA[row*512 + sp*8];
      }
      __builtin_amdgcn_s_setprio(1);
      #pragma unroll
      for (int fr = 0; fr < 4; ++fr)
        #pragma unroll
        for (int fc = 0; fc < 2; ++fc)
          acc[fr][fc] = __builtin_amdgcn_mfma_f32_16x16x32_bf16(a[fr], b[kk & 1][fc], acc[fr][fc], 0, 0, 0);
      __builtin_amdgcn_s_setprio(0);
      __builtin_amdgcn_sched_barrier(0);
      if (kk < 14){
        #pragma unroll
        for (int fc = 0; fc < 2; ++fc)
          b[kk & 1][fc] = *(const s16x8*)(pbase + (size_t)(kk+2)*1024 + fc*512 + loff);
      }
    }

    const float cwv0 = cwl[ci*256 + w*32 + 0*16 + lr];
    const float cwv1 = cwl[ci*256 + w*32 + 1*16 + lr];
    #pragma unroll
    for (int fr = 0; fr < 4; ++fr){
      #pragma unroll
      for (int r = 0; r < 4; ++r){
        const float e0 = __expf(acc[fr][0][r]);   // scale pre-folded into cb
        const float e1 = __expf(acc[fr][1][r]);
        es[fr][r] += e0 + e1;
        ws[fr][r] += e0 * cwv0 + e1 * cwv1;
      }
    }
  }

  // single 16-lane shuffle ladder, once per wave
  #pragma unroll
  for (int fr = 0; fr < 4; ++fr){
    #pragma unroll
    for (int r = 0; r < 4; ++r){
      float a0 = es[fr][r], b0 = ws[fr][r];
      #pragma unroll
      for (int m = 1; m < 16; m <<= 1){
        a0 += __shfl_xor(a0, m, 64);
        b0 += __shfl_xor(b0, m, 64);
      }
      if (lr == 0){
        const int row = fr*16 + kg*4 + r;   // C/D map: row=(l>>4)*4+reg
        pe[w][row] = a0;
        pw[w][row] = b0;
      }
    }
  }

  __syncthreads();
  if (t < 64){
    float se = 0.f, sw = 0.f;
    #pragma unroll
    for (int i = 0; i < 8; ++i){ se += pe[i][t]; sw += pw[i][t]; }
    const float e = sw / se;
    ew_out[m0 + t] = e;
    ewl[t] = e;
  }

  if constexpr (FUSE_V){
    __syncthreads();                       // ewl ready; sA dead -> reuse
    float* psum = (float*)sA;              // [4][512] f32 = 8 KB
    const int sh = t >> 7;                 // s-quarter 0..3
    const int dq = (t & 127) * 4;          // d offset
    const float* vb = Vp + (size_t)m0*512 + dq;
    f32x4 av = {0.f,0.f,0.f,0.f};
    #pragma unroll
    for (int i = 0; i < 16; ++i){
      const int s = sh*16 + i;
      av += ewl[s] * *(const f32x4*)(vb + (size_t)s*512);
    }
    *(f32x4*)&psum[sh*512 + dq] = av;
    __syncthreads();
    if (t < 128){
      const int d4 = t*4;
      f32x4 r = *(f32x4*)&psum[d4];
      r += *(f32x4*)&psum[512 + d4];
      r += *(f32x4*)&psum[1024 + d4];
      r += *(f32x4*)&psum[1536 + d4];
      *(f32x4*)&partial[(size_t)blockIdx.x*512 + d4] = r;
    }
  }
}

// ---------------------------------------------------------------------------
// Kernel C (fallback only): summary[n][d] = sum_s ew[n,s] * V[n,s,d].
// ---------------------------------------------------------------------------
__global__ __launch_bounds__(256) void k_summary(const float* __restrict__ V,
                                                 const float* __restrict__ ew,
                                                 float* __restrict__ sm){
  __shared__ float e[256];
  __shared__ f32x4 red[3][64];
  const int t = threadIdx.x;
  const int lane = t & 63, w = t >> 6;
  const int n = blockIdx.x >> 1;
  const int d0 = (blockIdx.x & 1) * 256;
  e[t] = ew[(size_t)n*256 + t];
  __syncthreads();
  const float* vb = V + (size_t)n*131072 + d0 + lane*4;
  f32x4 acc = {0.f,0.f,0.f,0.f};
  #pragma unroll 8
  for (int s = w; s < 256; s += 4){
    const f32x4 v = *(const f32x4*)(vb + (size_t)s*512);
    acc += e[s] * v;
  }
  if (w > 0) red[w-1][lane] = acc;
  __syncthreads();
  if (w == 0){
    acc += red[0][lane] + red[1][lane] + red[2][lane];
    *(f32x4*)(sm + (size_t)n*512 + d0 + lane*4) = acc;
  }
}

// ---------------------------------------------------------------------------
// Kernel D: logits/recon readout. FUSED: src = partial[2048][512], summary
// row ni = sum of 4 partials. Else src = sm[512][512].
// grid = 64 n-blocks (8 n) x 4 W-slices = 256 blocks.
// ---------------------------------------------------------------------------
template<bool FUSED>
__global__ __launch_bounds__(256) void k_readout(const float* __restrict__ src,
                                                 const float* __restrict__ Wc,
                                                 const float* __restrict__ bc,
                                                 const float* __restrict__ Wr,
                                                 const float* __restrict__ br,
                                                 float* __restrict__ logits,
                                                 float* __restrict__ recon){
  __shared__ __align__(16) float sl[8][512];
  const int t = threadIdx.x;
  const int nb  = blockIdx.x >> 2;
  const int wsl = blockIdx.x & 3;
  const int n0 = nb * 8;
  #pragma unroll
  for (int j = 0; j < 16; ++j){
    const int o = t + 256*j; const int ni = o >> 9, d = o & 511;
    if (FUSED){
      const float* pb = src + (size_t)(n0+ni)*2048 + d;
      sl[ni][d] = pb[0] + pb[512] + pb[1024] + pb[1536];
    } else {
      sl[ni][d] = src[(size_t)(n0+ni)*512 + d];
    }
  }
  __syncthreads();
  #pragma unroll 1
  for (int j = 0; j < 2; ++j){
    const int rel = t + 256*j;
    if (rel >= 378) continue;
    const int o = wsl*378 + rel;          // 0..1511
    const bool isl = o < 1000;
    const float* wrow = isl ? (Wc + (size_t)o*512) : (Wr + (size_t)(o-1000)*512);
    const float bias  = isl ? bc[o] : br[o-1000];
    const f32x4* w4 = (const f32x4*)wrow;
    f32x4 av[8];
    #pragma unroll
    for (int ni = 0; ni < 8; ++ni) av[ni] = (f32x4){0.f,0.f,0.f,0.f};
    for (int d = 0; d < 128; ++d){
      const f32x4 wv = w4[d];
      #pragma unroll
      for (int ni = 0; ni < 8; ++ni)
        av[ni] += wv * ((const f32x4*)sl[ni])[d];
    }
    #pragma unroll
    for (int ni = 0; ni < 8; ++ni){
      const float r = hsum4(av[ni]) + bias;
      if (isl) logits[(size_t)(n0+ni)*1000 + o] = r;
      else     recon [(size_t)(n0+ni)*512 + (o-1000)] = r;
    }
  }
}

extern "C" void kernel_launch(void* const* d_in, const int* in_sizes, int n_in,
                              void* d_out, int out_size, void* d_ws, size_t ws_size,
                              hipStream_t stream) {
  const float* q  = (const float*)d_in[0];
  const float* K  = (const float*)d_in[1];
  const float* V  = (const float*)d_in[2];
  const float* cb = (const float*)d_in[3];
  const float* Wq = (const float*)d_in[4];
  const float* Wc = (const float*)d_in[5];
  const float* bc = (const float*)d_in[6];
  const float* Wr = (const float*)d_in[7];
  const float* br = (const float*)d_in[8];

  float* out    = (float*)d_out;
  float* logits = out;                         // 512*1000
  float* recon  = out + 512*1000;              // 512*512
  float* ew     = out + 512*1000 + 512*512;    // 512*256

  char* wsb = (char*)d_ws;
  unsigned short* cbB = (unsigned short*)wsb;            // 1 MB
  float* cw   = (float*)(wsb + (1u<<20));                // 2 MB
  float* aux  = (float*)(wsb + 3u*(1u<<20));             // partials (4MB) or sm (1MB)

  const bool fused = ws_size >= (size_t)(7u<<20);

  k_prep<<<dim3(384), dim3(256), 0, stream>>>(cb, cbB, q, Wq, cw);
  if (fused){
    k_scores<true><<<dim3(2048), dim3(512), 0, stream>>>(K, cbB, cw, ew, V, aux);
    k_readout<true><<<dim3(256), dim3(256), 0, stream>>>(aux, Wc, bc, Wr, br, logits, recon);
  } else {
    k_scores<false><<<dim3(2048), dim3(512), 0, stream>>>(K, cbB, cw, ew, V, aux);
    k_summary<<<dim3(1024), dim3(256), 0, stream>>>(V, ew, aux);
    k_readout<false><<<dim3(256), dim3(256), 0, stream>>>(aux, Wc, bc, Wr, br, logits, recon);
  }
}